// Round 14
// baseline (173.980 us; speedup 1.0000x reference)
//
#include <hip/hip_runtime.h>

#define IMG_SIZE 256
#define NPIX (IMG_SIZE * IMG_SIZE)
#define KSEL 5
#define BS 8
#define LL 64
#define LUSED 63          // row l=63's top-k is discarded by the roll — never compute/write it
#define NTHREADS 256
#define SPLIT 8           // chunk splits per image (R13 calibration: need 8 blocks/CU at RPB=2)
#define CHUNK (NPIX / SPLIT)      // 8192 pixels per (b,split) slice
#define RPB 2             // rows (l values) amortized per block
#define RGRP (LL / RPB)   // 32 row-groups
#define NBLK2 (BS * SPLIT * RGRP)         // 2048 blocks = 8/CU x 4 waves = 32 waves/CU (full)
#define QCAP 576          // per-wave tagged queue; 4*576*8 = 18432 B; x8 blocks = 148KB <= 160KB LDS
#define SENTK 0xFFFFFFFFFFFFFFFFULL

typedef unsigned long long ull;

// Branchless sorted-insert: loc[] ascending; bubble key in, evict the max.
// Static indices only -> stays in VGPRs; no divergence.
__device__ __forceinline__ void sort_insert(ull loc[KSEL], ull key) {
    #pragma unroll
    for (int j = 0; j < KSEL; ++j) {
        const ull a = loc[j];
        const bool lt = key < a;
        loc[j] = lt ? key : a;
        key    = lt ? a : key;
    }
}

// Merge two ascending 5-lists, keep smallest 5 into a.
__device__ __forceinline__ void merge5(ull* a, const ull* b) {
    ull out[KSEL];
    int ia = 0, ib = 0;
    #pragma unroll
    for (int j = 0; j < KSEL; ++j) {
        const ull va = a[ia], vb = b[ib];
        const bool ta = va <= vb;
        out[j] = ta ? va : vb;
        ia += ta ? 1 : 0;
        ib += ta ? 0 : 1;
    }
    #pragma unroll
    for (int j = 0; j < KSEL; ++j) a[j] = out[j];
}

// Single source of truth for the SSD: match numpy f32 exactly — no FMA
// contraction, ((d0^2+d1^2)+d2^2). Bootstrap keys and steady-path gate both
// use THIS function, so gate-s and key-s are bit-identical.
__device__ __forceinline__ float
pix_s(float r0, float r1, float r2, float c0, float c1, float c2) {
    float d0 = __fsub_rn(r0, c0);
    float d1 = __fsub_rn(r1, c1);
    float d2 = __fsub_rn(r2, c2);
    return __fadd_rn(__fadd_rn(__fmul_rn(d0, d0), __fmul_rn(d1, d1)), __fmul_rn(d2, d2));
}

__device__ __forceinline__ ull
pix_key(float r0, float r1, float r2, float c0, float c1, float c2, int pix) {
    // s >= 0 (sum of squares) -> uint bit order == float order; low bits = pixel
    // index gives jax top_k's lower-index-first tie-break.
    const float s = pix_s(r0, r1, r2, c0, c1, c2);
    return ((ull)__float_as_uint(s) << 32) | (unsigned int)pix;
}

// One block per (b, split, row-pair). Verified R13 kernel reparameterized:
// SPLIT 4 -> 8 so the grid is 2048 = 8 blocks/CU co-resident (32 waves/CU,
// the R9 TLP level) at the HALVED traffic of RPB=2 (198 MB vs R9's 396 MB).
// R13 calibration: topk time ~ traffic/TLP; R13 lost R12's traffic gain by
// running 16 waves/CU. LDS 18.5KB*8 = 148KB fits; launch_bounds(,8) caps
// VGPR at 64 (RPB=2 state ~52). No XCD swizzle (R11), no cross-block sync
// (R10), no divergent insert in the steady path (R7/R8).
// Queue entries carry a 1-bit row tag at bit 16 (pix < 2^16); pure key is
// reconstructed on drain, inserted via static 2-way branch (loc stays in
// registers). Exactness per row r (verified R8/R9/R12/R13):
//   thr[r] = bits of 5th-smallest s over the 1024-px bootstrap >= s5_chunk;
//   admit iff bits(s) <= thr[r] => every true top-5 key is in bootstrap∪queue;
//   each pixel tested once per row, each queue entry inserted once
//   => bit-identical top-5 per (row, split).
__global__ __launch_bounds__(NTHREADS, 8)
void topk_kernel(const float* __restrict__ preds,
                 const float* __restrict__ imgs,
                 ull* __restrict__ keys_out) {
    const int blk = blockIdx.x;
    const int split = blk & (SPLIT - 1);
    const int q2 = blk >> 3;
    const int b = q2 & (BS - 1);
    const int rg = q2 >> 3;              // 0 .. RGRP-1
    const int t = threadIdx.x;
    const int wave = t >> 6;
    const int lane = t & 63;

    __shared__ union ShMem {
        ull qq[4][QCAP];                 // 18432 B: per-wave tagged queues
        ull sk[NTHREADS * KSEL];         // 10240 B: merge scratch (aliases qq)
    } shm;
    __shared__ unsigned wcnt[4];

    if (t < 4) wcnt[t] = 0u;

    const float* imgb = imgs + (size_t)b * 3 * NPIX;

    // Per-row pooled colors (verified scrambled indexing: flat i = l*bs + b).
    float c0v[RPB], c1v[RPB], c2v[RPB];
    #pragma unroll
    for (int r = 0; r < RPB; ++r) {
        const int l = rg * RPB + r;      // l = 63 computed, never written
        const int i = l * BS + b;
        const int pb = i >> 6;
        const int pl = i & 63;
        const float px = preds[pb * (LL * 8) + pl * 8 + 0];
        const float py = preds[pb * (LL * 8) + pl * 8 + 1];
        // grid_sample nearest, align_corners=False, zeros padding.
        const float cx = __fsub_rn(__fmul_rn(px, 256.0f), 0.5f);
        const float cy = __fsub_rn(__fmul_rn(py, 256.0f), 0.5f);
        const int ix = (int)rintf(cx);   // round half to even == jnp.rint
        const int iy = (int)rintf(cy);
        const bool valid = (ix >= 0) && (ix < IMG_SIZE) && (iy >= 0) && (iy < IMG_SIZE);
        const int ixc = min(max(ix, 0), IMG_SIZE - 1);
        const int iyc = min(max(iy, 0), IMG_SIZE - 1);
        const float vmul = valid ? 1.0f : 0.0f;
        c0v[r] = imgb[0 * NPIX + iyc * IMG_SIZE + ixc] * vmul;
        c1v[r] = imgb[1 * NPIX + iyc * IMG_SIZE + ixc] * vmul;
        c2v[r] = imgb[2 * NPIX + iyc * IMG_SIZE + ixc] * vmul;
    }

    const float4* p0 = (const float4*)(imgb + 0 * NPIX);
    const float4* p1 = (const float4*)(imgb + 1 * NPIX);
    const float4* p2 = (const float4*)(imgb + 2 * NPIX);

    ull loc[RPB][KSEL];                  // unrolled row loops -> registers
    #pragma unroll
    for (int r = 0; r < RPB; ++r)
        #pragma unroll
        for (int j = 0; j < KSEL; ++j) loc[r][j] = SENTK;

    const int v0 = split * (CHUNK / 4);

    // ---- Bootstrap: iteration 0 (1024 px), unconditional inserts x 2 rows ----
    {
        const int v = v0 + t;
        const float4 r0 = p0[v];
        const float4 r1 = p1[v];
        const float4 r2 = p2[v];
        const int base = v * 4;
        #pragma unroll
        for (int r = 0; r < RPB; ++r) {
            sort_insert(loc[r], pix_key(r0.x, r1.x, r2.x, c0v[r], c1v[r], c2v[r], base + 0));
            sort_insert(loc[r], pix_key(r0.y, r1.y, r2.y, c0v[r], c1v[r], c2v[r], base + 1));
            sort_insert(loc[r], pix_key(r0.z, r1.z, r2.z, c0v[r], c1v[r], c2v[r], base + 2));
            sort_insert(loc[r], pix_key(r0.w, r1.w, r2.w, c0v[r], c1v[r], c2v[r], base + 3));
        }
    }

    // ---- Per-row block-exact bootstrap thresholds (verified merge5 tree x2) ----
    unsigned thrv[RPB];
    __syncthreads();                     // wcnt init + before first sk use
    #pragma unroll
    for (int r = 0; r < RPB; ++r) {
        #pragma unroll
        for (int j = 0; j < KSEL; ++j) shm.sk[t * KSEL + j] = loc[r][j];
        __syncthreads();
        for (int s = NTHREADS / 2; s > 0; s >>= 1) {
            if (t < s) {
                ull a[KSEL], bb[KSEL];
                #pragma unroll
                for (int j = 0; j < KSEL; ++j) { a[j] = shm.sk[t * KSEL + j]; bb[j] = shm.sk[(t + s) * KSEL + j]; }
                merge5(a, bb);
                #pragma unroll
                for (int j = 0; j < KSEL; ++j) shm.sk[t * KSEL + j] = a[j];
            }
            __syncthreads();
        }
        thrv[r] = (unsigned)(shm.sk[KSEL - 1] >> 32);   // bits of s5(bootstrap, row r)
        __syncthreads();                 // all read sk[4] before next overwrite
    }
    if (t < 4) wcnt[t] = 0u;             // queue region (aliases sk) about to be used
    __syncthreads();

    // Drain helper: pop tagged entries into the right row list (static branch).
    auto drain = [&]() {
        const unsigned n = wcnt[wave];
        for (unsigned o = lane; o < n; o += 64) {
            const ull e = shm.qq[wave][o];
            const ull key = (e & 0xFFFFFFFF00000000ULL) | (e & 0xFFFFULL);
            if (((e >> 16) & 1ULL) == 0) sort_insert(loc[0], key);
            else                         sort_insert(loc[1], key);
        }
    };

    // ---- Steady loop: dense loads amortized over 2 rows; 9-op s per row;
    //      rare tagged queue push (no insert, no ballot in the hot path) ----
    #pragma unroll 2
    for (int it = 1; it < CHUNK / 4 / NTHREADS; ++it) {
        // Overflow safety (wave-uniform; worst case 64 lanes*4px*2rows = 512/iter).
        if (wcnt[wave] > QCAP - 2 * NTHREADS) {
            drain();
            if (lane == 0) wcnt[wave] = 0u;   // per-wave LDS ops in order: reads precede
        }
        const int v = v0 + it * NTHREADS + t;
        const float4 r0 = p0[v];
        const float4 r1 = p1[v];
        const float4 r2 = p2[v];
        const int base = v * 4;

        #pragma unroll
        for (int r = 0; r < RPB; ++r) {
            const float s0 = pix_s(r0.x, r1.x, r2.x, c0v[r], c1v[r], c2v[r]);
            const float s1 = pix_s(r0.y, r1.y, r2.y, c0v[r], c1v[r], c2v[r]);
            const float s2 = pix_s(r0.z, r1.z, r2.z, c0v[r], c1v[r], c2v[r]);
            const float s3 = pix_s(r0.w, r1.w, r2.w, c0v[r], c1v[r], c2v[r]);
            if (__float_as_uint(s0) <= thrv[r]) {
                const unsigned pos = atomicAdd(&wcnt[wave], 1u);
                shm.qq[wave][pos] = ((ull)__float_as_uint(s0) << 32) | ((ull)r << 16) | (unsigned)(base + 0);
            }
            if (__float_as_uint(s1) <= thrv[r]) {
                const unsigned pos = atomicAdd(&wcnt[wave], 1u);
                shm.qq[wave][pos] = ((ull)__float_as_uint(s1) << 32) | ((ull)r << 16) | (unsigned)(base + 1);
            }
            if (__float_as_uint(s2) <= thrv[r]) {
                const unsigned pos = atomicAdd(&wcnt[wave], 1u);
                shm.qq[wave][pos] = ((ull)__float_as_uint(s2) << 32) | ((ull)r << 16) | (unsigned)(base + 2);
            }
            if (__float_as_uint(s3) <= thrv[r]) {
                const unsigned pos = atomicAdd(&wcnt[wave], 1u);
                shm.qq[wave][pos] = ((ull)__float_as_uint(s3) << 32) | ((ull)r << 16) | (unsigned)(base + 3);
            }
        }
    }

    // ---- End drain, then per-row verified merge trees + key output ----
    drain();
    __syncthreads();                     // all drains done before sk (alias) reuse
    #pragma unroll
    for (int r = 0; r < RPB; ++r) {
        const int l = rg * RPB + r;
        #pragma unroll
        for (int j = 0; j < KSEL; ++j) shm.sk[t * KSEL + j] = loc[r][j];
        __syncthreads();
        for (int s = NTHREADS / 2; s > 0; s >>= 1) {
            if (t < s) {
                ull a[KSEL], bb[KSEL];
                #pragma unroll
                for (int j = 0; j < KSEL; ++j) { a[j] = shm.sk[t * KSEL + j]; bb[j] = shm.sk[(t + s) * KSEL + j]; }
                merge5(a, bb);
                #pragma unroll
                for (int j = 0; j < KSEL; ++j) shm.sk[t * KSEL + j] = a[j];
            }
            __syncthreads();
        }
        if (l < LUSED && t < KSEL) {
            keys_out[((size_t)(b * LL + l) * SPLIT + split) * KSEL + t] = shm.sk[t];
        }
        __syncthreads();                 // writes read before next row overwrites sk
    }
}

// Epilogue (verified, unchanged; SPLIT flows through): merge the SPLIT partial
// top-5s per row, roll along L, min positional distance over the 5 selected
// pixels, mean.
__global__ __launch_bounds__(NTHREADS)
void finalize_kernel(const float* __restrict__ preds,
                     const ull* __restrict__ keys,
                     float* __restrict__ out) {
    const int t = threadIdx.x;
    float acc = 0.0f;

    for (int p = t; p < BS * LUSED; p += NTHREADS) {
        const int b = p / LUSED;
        const int l = p % LUSED + 1;              // loss rows: l = 1..63
        const float px = preds[b * (LL * 8) + l * 8 + 0];
        const float py = preds[b * (LL * 8) + l * 8 + 1];

        // tgt_down[:, l] = tgt[:, l-1]: merge the SPLIT sorted 5-lists of row l-1.
        const int srow = b * LL + (l - 1);
        ull loc[KSEL];
        #pragma unroll
        for (int j = 0; j < KSEL; ++j) loc[j] = SENTK;
        #pragma unroll
        for (int s = 0; s < SPLIT; ++s) {
            #pragma unroll
            for (int k = 0; k < KSEL; ++k) {
                sort_insert(loc, keys[((size_t)srow * SPLIT + s) * KSEL + k]);
            }
        }

        float best = 3.4028235e38f;
        #pragma unroll
        for (int k = 0; k < KSEL; ++k) {
            const int ixk = (int)(loc[k] & 0xFFFFFFFFULL);
            const float tx = (float)(ixk & 255) * (1.0f / 256.0f);   // exact /256
            const float ty = (float)(ixk >> 8) * (1.0f / 256.0f);
            const float dx = __fsub_rn(px, tx);
            const float dy = __fsub_rn(py, ty);
            const float dist = __fadd_rn(__fmul_rn(dx, dx), __fmul_rn(dy, dy));
            best = dist < best ? dist : best;
        }
        acc += best;
    }

    __shared__ float red[NTHREADS];
    red[t] = acc;
    __syncthreads();
    for (int s = NTHREADS / 2; s > 0; s >>= 1) {
        if (t < s) red[t] += red[t + s];
        __syncthreads();
    }
    if (t == 0) {
        out[0] = red[0] / (float)(BS * (LL - 1));
    }
}

extern "C" void kernel_launch(void* const* d_in, const int* in_sizes, int n_in,
                              void* d_out, int out_size, void* d_ws, size_t ws_size,
                              hipStream_t stream) {
    const float* preds = (const float*)d_in[0];   // (8, 64, 8) f32
    const float* imgs  = (const float*)d_in[1];   // (8, 3, 256, 256) f32
    float* out = (float*)d_out;                   // scalar f32
    ull* keys = (ull*)d_ws;                       // 512 * SPLIT * 5 u64 = 160 KB

    topk_kernel<<<dim3(NBLK2), dim3(NTHREADS), 0, stream>>>(preds, imgs, keys);
    finalize_kernel<<<dim3(1), dim3(NTHREADS), 0, stream>>>(preds, keys, out);
}

// Round 15
// 106.657 us; speedup vs baseline: 1.6312x; 1.6312x over previous
//
#include <hip/hip_runtime.h>

#define IMG_SIZE 256
#define NPIX (IMG_SIZE * IMG_SIZE)
#define KSEL 5
#define BS 8
#define LL 64
#define LUSED 63          // row l=63's top-k is discarded by the roll — never compute/write it
#define NTHREADS 256
#define SPLIT 8           // chunk splits per image (2048 blocks -> full co-residency at RPB=2)
#define CHUNK (NPIX / SPLIT)      // 8192 pixels per (b,split) slice
#define RPB 2             // rows (l values) amortized per block
#define RGRP (LL / RPB)   // 32 row-groups
#define NBLK2 (BS * SPLIT * RGRP)         // 2048 blocks
#define QCAP 576          // per-wave tagged queue; 4*576*8 = 18432 B LDS
#define SENTK 0xFFFFFFFFFFFFFFFFULL

typedef unsigned long long ull;

// Branchless sorted-insert: loc[] ascending; bubble key in, evict the max.
// Static indices only -> stays in VGPRs; no divergence.
__device__ __forceinline__ void sort_insert(ull loc[KSEL], ull key) {
    #pragma unroll
    for (int j = 0; j < KSEL; ++j) {
        const ull a = loc[j];
        const bool lt = key < a;
        loc[j] = lt ? key : a;
        key    = lt ? a : key;
    }
}

// Merge two ascending 5-lists, keep smallest 5 into a.
__device__ __forceinline__ void merge5(ull* a, const ull* b) {
    ull out[KSEL];
    int ia = 0, ib = 0;
    #pragma unroll
    for (int j = 0; j < KSEL; ++j) {
        const ull va = a[ia], vb = b[ib];
        const bool ta = va <= vb;
        out[j] = ta ? va : vb;
        ia += ta ? 1 : 0;
        ib += ta ? 0 : 1;
    }
    #pragma unroll
    for (int j = 0; j < KSEL; ++j) a[j] = out[j];
}

// Single source of truth for the SSD: match numpy f32 exactly — no FMA
// contraction, ((d0^2+d1^2)+d2^2). Bootstrap keys and steady-path gate both
// use THIS function, so gate-s and key-s are bit-identical.
__device__ __forceinline__ float
pix_s(float r0, float r1, float r2, float c0, float c1, float c2) {
    float d0 = __fsub_rn(r0, c0);
    float d1 = __fsub_rn(r1, c1);
    float d2 = __fsub_rn(r2, c2);
    return __fadd_rn(__fadd_rn(__fmul_rn(d0, d0), __fmul_rn(d1, d1)), __fmul_rn(d2, d2));
}

__device__ __forceinline__ ull
pix_key(float r0, float r1, float r2, float c0, float c1, float c2, int pix) {
    // s >= 0 (sum of squares) -> uint bit order == float order; low bits = pixel
    // index gives jax top_k's lower-index-first tie-break.
    const float s = pix_s(r0, r1, r2, c0, c1, c2);
    return ((ull)__float_as_uint(s) << 32) | (unsigned int)pix;
}

// One block per (b, split, row-pair). Identical to the R14 kernel (selection
// verified: absmax 0.0) EXCEPT the launch bound: R14's __launch_bounds__(,8)
// capped VGPRs at 64 < the ~70 the RPB=2 state needs -> compiler spilled the
// hot lists to scratch (counters: VGPR_Count 32, WRITE_SIZE 204MB, FETCH
// 54MB, 116us). Plain __launch_bounds__(256) lets the compiler take ~68
// VGPRs: no spill, occupancy = min(LDS 8/CU, VGPR ~7/CU) ~ 28 waves/CU —
// near-R9 TLP at HALF R9's L2/L3 traffic (198 vs 396 MB). Calibration
// (R9/R13: time ~ traffic/TLP) predicts topk ~ 15-18us.
// No XCD swizzle (R11), no cross-block sync (R10), no divergent insert in
// the steady path (R7/R8).
// Queue entries carry a 1-bit row tag at bit 16 (pix < 2^16); pure key is
// reconstructed on drain, inserted via static 2-way branch (loc stays in
// registers). Exactness per row r (verified R8/R9/R12/R13/R14):
//   thr[r] = bits of 5th-smallest s over the 1024-px bootstrap >= s5_chunk;
//   admit iff bits(s) <= thr[r] => every true top-5 key is in bootstrap∪queue;
//   each pixel tested once per row, each queue entry inserted once
//   => bit-identical top-5 per (row, split).
__global__ __launch_bounds__(NTHREADS)
void topk_kernel(const float* __restrict__ preds,
                 const float* __restrict__ imgs,
                 ull* __restrict__ keys_out) {
    const int blk = blockIdx.x;
    const int split = blk & (SPLIT - 1);
    const int q2 = blk >> 3;
    const int b = q2 & (BS - 1);
    const int rg = q2 >> 3;              // 0 .. RGRP-1
    const int t = threadIdx.x;
    const int wave = t >> 6;
    const int lane = t & 63;

    __shared__ union ShMem {
        ull qq[4][QCAP];                 // 18432 B: per-wave tagged queues
        ull sk[NTHREADS * KSEL];         // 10240 B: merge scratch (aliases qq)
    } shm;
    __shared__ unsigned wcnt[4];

    if (t < 4) wcnt[t] = 0u;

    const float* imgb = imgs + (size_t)b * 3 * NPIX;

    // Per-row pooled colors (verified scrambled indexing: flat i = l*bs + b).
    float c0v[RPB], c1v[RPB], c2v[RPB];
    #pragma unroll
    for (int r = 0; r < RPB; ++r) {
        const int l = rg * RPB + r;      // l = 63 computed, never written
        const int i = l * BS + b;
        const int pb = i >> 6;
        const int pl = i & 63;
        const float px = preds[pb * (LL * 8) + pl * 8 + 0];
        const float py = preds[pb * (LL * 8) + pl * 8 + 1];
        // grid_sample nearest, align_corners=False, zeros padding.
        const float cx = __fsub_rn(__fmul_rn(px, 256.0f), 0.5f);
        const float cy = __fsub_rn(__fmul_rn(py, 256.0f), 0.5f);
        const int ix = (int)rintf(cx);   // round half to even == jnp.rint
        const int iy = (int)rintf(cy);
        const bool valid = (ix >= 0) && (ix < IMG_SIZE) && (iy >= 0) && (iy < IMG_SIZE);
        const int ixc = min(max(ix, 0), IMG_SIZE - 1);
        const int iyc = min(max(iy, 0), IMG_SIZE - 1);
        const float vmul = valid ? 1.0f : 0.0f;
        c0v[r] = imgb[0 * NPIX + iyc * IMG_SIZE + ixc] * vmul;
        c1v[r] = imgb[1 * NPIX + iyc * IMG_SIZE + ixc] * vmul;
        c2v[r] = imgb[2 * NPIX + iyc * IMG_SIZE + ixc] * vmul;
    }

    const float4* p0 = (const float4*)(imgb + 0 * NPIX);
    const float4* p1 = (const float4*)(imgb + 1 * NPIX);
    const float4* p2 = (const float4*)(imgb + 2 * NPIX);

    ull loc[RPB][KSEL];                  // unrolled row loops -> registers
    #pragma unroll
    for (int r = 0; r < RPB; ++r)
        #pragma unroll
        for (int j = 0; j < KSEL; ++j) loc[r][j] = SENTK;

    const int v0 = split * (CHUNK / 4);

    // ---- Bootstrap: iteration 0 (1024 px), unconditional inserts x 2 rows ----
    {
        const int v = v0 + t;
        const float4 r0 = p0[v];
        const float4 r1 = p1[v];
        const float4 r2 = p2[v];
        const int base = v * 4;
        #pragma unroll
        for (int r = 0; r < RPB; ++r) {
            sort_insert(loc[r], pix_key(r0.x, r1.x, r2.x, c0v[r], c1v[r], c2v[r], base + 0));
            sort_insert(loc[r], pix_key(r0.y, r1.y, r2.y, c0v[r], c1v[r], c2v[r], base + 1));
            sort_insert(loc[r], pix_key(r0.z, r1.z, r2.z, c0v[r], c1v[r], c2v[r], base + 2));
            sort_insert(loc[r], pix_key(r0.w, r1.w, r2.w, c0v[r], c1v[r], c2v[r], base + 3));
        }
    }

    // ---- Per-row block-exact bootstrap thresholds (verified merge5 tree x2) ----
    unsigned thrv[RPB];
    __syncthreads();                     // wcnt init + before first sk use
    #pragma unroll
    for (int r = 0; r < RPB; ++r) {
        #pragma unroll
        for (int j = 0; j < KSEL; ++j) shm.sk[t * KSEL + j] = loc[r][j];
        __syncthreads();
        for (int s = NTHREADS / 2; s > 0; s >>= 1) {
            if (t < s) {
                ull a[KSEL], bb[KSEL];
                #pragma unroll
                for (int j = 0; j < KSEL; ++j) { a[j] = shm.sk[t * KSEL + j]; bb[j] = shm.sk[(t + s) * KSEL + j]; }
                merge5(a, bb);
                #pragma unroll
                for (int j = 0; j < KSEL; ++j) shm.sk[t * KSEL + j] = a[j];
            }
            __syncthreads();
        }
        thrv[r] = (unsigned)(shm.sk[KSEL - 1] >> 32);   // bits of s5(bootstrap, row r)
        __syncthreads();                 // all read sk[4] before next overwrite
    }
    if (t < 4) wcnt[t] = 0u;             // queue region (aliases sk) about to be used
    __syncthreads();

    // Drain helper: pop tagged entries into the right row list (static branch).
    auto drain = [&]() {
        const unsigned n = wcnt[wave];
        for (unsigned o = lane; o < n; o += 64) {
            const ull e = shm.qq[wave][o];
            const ull key = (e & 0xFFFFFFFF00000000ULL) | (e & 0xFFFFULL);
            if (((e >> 16) & 1ULL) == 0) sort_insert(loc[0], key);
            else                         sort_insert(loc[1], key);
        }
    };

    // ---- Steady loop: dense loads amortized over 2 rows; 9-op s per row;
    //      rare tagged queue push (no insert, no ballot in the hot path) ----
    #pragma unroll 2
    for (int it = 1; it < CHUNK / 4 / NTHREADS; ++it) {
        // Overflow safety (wave-uniform; worst case 64 lanes*4px*2rows = 512/iter).
        if (wcnt[wave] > QCAP - 2 * NTHREADS) {
            drain();
            if (lane == 0) wcnt[wave] = 0u;   // per-wave LDS ops in order: reads precede
        }
        const int v = v0 + it * NTHREADS + t;
        const float4 r0 = p0[v];
        const float4 r1 = p1[v];
        const float4 r2 = p2[v];
        const int base = v * 4;

        #pragma unroll
        for (int r = 0; r < RPB; ++r) {
            const float s0 = pix_s(r0.x, r1.x, r2.x, c0v[r], c1v[r], c2v[r]);
            const float s1 = pix_s(r0.y, r1.y, r2.y, c0v[r], c1v[r], c2v[r]);
            const float s2 = pix_s(r0.z, r1.z, r2.z, c0v[r], c1v[r], c2v[r]);
            const float s3 = pix_s(r0.w, r1.w, r2.w, c0v[r], c1v[r], c2v[r]);
            if (__float_as_uint(s0) <= thrv[r]) {
                const unsigned pos = atomicAdd(&wcnt[wave], 1u);
                shm.qq[wave][pos] = ((ull)__float_as_uint(s0) << 32) | ((ull)r << 16) | (unsigned)(base + 0);
            }
            if (__float_as_uint(s1) <= thrv[r]) {
                const unsigned pos = atomicAdd(&wcnt[wave], 1u);
                shm.qq[wave][pos] = ((ull)__float_as_uint(s1) << 32) | ((ull)r << 16) | (unsigned)(base + 1);
            }
            if (__float_as_uint(s2) <= thrv[r]) {
                const unsigned pos = atomicAdd(&wcnt[wave], 1u);
                shm.qq[wave][pos] = ((ull)__float_as_uint(s2) << 32) | ((ull)r << 16) | (unsigned)(base + 2);
            }
            if (__float_as_uint(s3) <= thrv[r]) {
                const unsigned pos = atomicAdd(&wcnt[wave], 1u);
                shm.qq[wave][pos] = ((ull)__float_as_uint(s3) << 32) | ((ull)r << 16) | (unsigned)(base + 3);
            }
        }
    }

    // ---- End drain, then per-row verified merge trees + key output ----
    drain();
    __syncthreads();                     // all drains done before sk (alias) reuse
    #pragma unroll
    for (int r = 0; r < RPB; ++r) {
        const int l = rg * RPB + r;
        #pragma unroll
        for (int j = 0; j < KSEL; ++j) shm.sk[t * KSEL + j] = loc[r][j];
        __syncthreads();
        for (int s = NTHREADS / 2; s > 0; s >>= 1) {
            if (t < s) {
                ull a[KSEL], bb[KSEL];
                #pragma unroll
                for (int j = 0; j < KSEL; ++j) { a[j] = shm.sk[t * KSEL + j]; bb[j] = shm.sk[(t + s) * KSEL + j]; }
                merge5(a, bb);
                #pragma unroll
                for (int j = 0; j < KSEL; ++j) shm.sk[t * KSEL + j] = a[j];
            }
            __syncthreads();
        }
        if (l < LUSED && t < KSEL) {
            keys_out[((size_t)(b * LL + l) * SPLIT + split) * KSEL + t] = shm.sk[t];
        }
        __syncthreads();                 // writes read before next row overwrites sk
    }
}

// Epilogue (verified, unchanged; SPLIT flows through): merge the SPLIT partial
// top-5s per row, roll along L, min positional distance over the 5 selected
// pixels, mean.
__global__ __launch_bounds__(NTHREADS)
void finalize_kernel(const float* __restrict__ preds,
                     const ull* __restrict__ keys,
                     float* __restrict__ out) {
    const int t = threadIdx.x;
    float acc = 0.0f;

    for (int p = t; p < BS * LUSED; p += NTHREADS) {
        const int b = p / LUSED;
        const int l = p % LUSED + 1;              // loss rows: l = 1..63
        const float px = preds[b * (LL * 8) + l * 8 + 0];
        const float py = preds[b * (LL * 8) + l * 8 + 1];

        // tgt_down[:, l] = tgt[:, l-1]: merge the SPLIT sorted 5-lists of row l-1.
        const int srow = b * LL + (l - 1);
        ull loc[KSEL];
        #pragma unroll
        for (int j = 0; j < KSEL; ++j) loc[j] = SENTK;
        #pragma unroll
        for (int s = 0; s < SPLIT; ++s) {
            #pragma unroll
            for (int k = 0; k < KSEL; ++k) {
                sort_insert(loc, keys[((size_t)srow * SPLIT + s) * KSEL + k]);
            }
        }

        float best = 3.4028235e38f;
        #pragma unroll
        for (int k = 0; k < KSEL; ++k) {
            const int ixk = (int)(loc[k] & 0xFFFFFFFFULL);
            const float tx = (float)(ixk & 255) * (1.0f / 256.0f);   // exact /256
            const float ty = (float)(ixk >> 8) * (1.0f / 256.0f);
            const float dx = __fsub_rn(px, tx);
            const float dy = __fsub_rn(py, ty);
            const float dist = __fadd_rn(__fmul_rn(dx, dx), __fmul_rn(dy, dy));
            best = dist < best ? dist : best;
        }
        acc += best;
    }

    __shared__ float red[NTHREADS];
    red[t] = acc;
    __syncthreads();
    for (int s = NTHREADS / 2; s > 0; s >>= 1) {
        if (t < s) red[t] += red[t + s];
        __syncthreads();
    }
    if (t == 0) {
        out[0] = red[0] / (float)(BS * (LL - 1));
    }
}

extern "C" void kernel_launch(void* const* d_in, const int* in_sizes, int n_in,
                              void* d_out, int out_size, void* d_ws, size_t ws_size,
                              hipStream_t stream) {
    const float* preds = (const float*)d_in[0];   // (8, 64, 8) f32
    const float* imgs  = (const float*)d_in[1];   // (8, 3, 256, 256) f32
    float* out = (float*)d_out;                   // scalar f32
    ull* keys = (ull*)d_ws;                       // 512 * SPLIT * 5 u64 = 160 KB

    topk_kernel<<<dim3(NBLK2), dim3(NTHREADS), 0, stream>>>(preds, imgs, keys);
    finalize_kernel<<<dim3(1), dim3(NTHREADS), 0, stream>>>(preds, keys, out);
}

// Round 16
// 102.988 us; speedup vs baseline: 1.6893x; 1.0356x over previous
//
#include <hip/hip_runtime.h>

#define IMG_SIZE 256
#define NPIX (IMG_SIZE * IMG_SIZE)
#define KSEL 5
#define BS 8
#define LL 64
#define LUSED 63          // row l=63's top-k is discarded by the roll — never compute it
#define NTHREADS 256
#define SPLIT 4           // blocks per (b,l) row (champion R9 geometry)
#define CHUNK (NPIX / SPLIT)      // 16384 pixels per block
#define NITER (CHUNK / 4 / NTHREADS)      // 16 float4-groups per thread
#define QCAP 320          // per-wave candidate queue; 4*QCAP*8 == NTHREADS*KSEL*8
#define SENTK 0xFFFFFFFFFFFFFFFFULL

typedef unsigned long long ull;

// Branchless sorted-insert: loc[] ascending; bubble key in, evict the max.
// Static indices only -> stays in VGPRs; no divergence.
__device__ __forceinline__ void sort_insert(ull loc[KSEL], ull key) {
    #pragma unroll
    for (int j = 0; j < KSEL; ++j) {
        const ull a = loc[j];
        const bool lt = key < a;
        loc[j] = lt ? key : a;
        key    = lt ? a : key;
    }
}

// Merge two ascending 5-lists, keep smallest 5 into a.
__device__ __forceinline__ void merge5(ull* a, const ull* b) {
    ull out[KSEL];
    int ia = 0, ib = 0;
    #pragma unroll
    for (int j = 0; j < KSEL; ++j) {
        const ull va = a[ia], vb = b[ib];
        const bool ta = va <= vb;
        out[j] = ta ? va : vb;
        ia += ta ? 1 : 0;
        ib += ta ? 0 : 1;
    }
    #pragma unroll
    for (int j = 0; j < KSEL; ++j) a[j] = out[j];
}

// Single source of truth for the SSD: match numpy f32 exactly — no FMA
// contraction, ((d0^2+d1^2)+d2^2). Bootstrap keys and steady-path gate both
// use THIS function, so gate-s and key-s are bit-identical.
__device__ __forceinline__ float
pix_s(float r0, float r1, float r2, float c0, float c1, float c2) {
    float d0 = __fsub_rn(r0, c0);
    float d1 = __fsub_rn(r1, c1);
    float d2 = __fsub_rn(r2, c2);
    return __fadd_rn(__fadd_rn(__fmul_rn(d0, d0), __fmul_rn(d1, d1)), __fmul_rn(d2, d2));
}

__device__ __forceinline__ ull
pix_key(float r0, float r1, float r2, float c0, float c1, float c2, int pix) {
    // s >= 0 (sum of squares) -> uint bit order == float order; low bits = pixel
    // index gives jax top_k's lower-index-first tie-break.
    const float s = pix_s(r0, r1, r2, c0, c1, c2);
    return ((ull)__float_as_uint(s) << 32) | (unsigned int)pix;
}

// One block per (b,l,split): the verified R9 champion (89.5us) with ONE
// change — steady-loop MLP widened from 3 to 6 in-flight loads (pixels it
// and it+1 loaded back-to-back, then both halves gated). R9's steady loop is
// latency-bound: 3 loads / ~50 insts / ~450cy L3 latency needs ~9 waves/SIMD
// to hide; we have 8. Pairing halves the per-load instruction distance.
// Same pixel set, same math; the queue guard runs before EACH half's <=256
// pushes (identical semantics to R9's per-iteration guard). Persistent VGPR
// ~50 < the 64 ceiling of launch_bounds(,8) -> no spill (R14 lesson checked).
// Geometry/LDS/keys layout byte-identical to R9.
// Exactness (verified R8/R9/R12/R13/R14/R15):
//   thr = bits of 5th-smallest s over the 1024-px bootstrap >= s5_chunk;
//   admit iff bits(s) <= thr => every true top-5 key is in bootstrap ∪ queue;
//   each pixel enters exactly once; each queue entry inserted once
//   => bit-identical top-5 per (row, split).
__global__ __launch_bounds__(NTHREADS, 8)
void topk_kernel(const float* __restrict__ preds,
                 const float* __restrict__ imgs,
                 ull* __restrict__ keys_out) {
    const int blk = blockIdx.x;
    const int split = blk & (SPLIT - 1);
    const int row = blk / SPLIT;         // 0 .. BS*LUSED-1
    const int b = row / LUSED;
    const int l = row % LUSED;
    const int bid = b * LL + l;          // storage row (l < 63)
    const int t = threadIdx.x;
    const int wave = t >> 6;
    const int lane = t & 63;

    __shared__ union ShMem {
        ull sk[NTHREADS * KSEL];         // 10240 B: merge scratch
        ull qq[4][QCAP];                 // 10240 B: per-wave candidate queues
    } shm;
    __shared__ unsigned wcnt[4];
    __shared__ unsigned thrsh;

    if (t < 4) wcnt[t] = 0u;

    // Scrambled pooled indexing: flat i = l*bs + b; position from preds[i//L, i%L].
    const int i = l * BS + b;
    const int pb = i >> 6;
    const int pl = i & 63;
    const float px = preds[pb * (LL * 8) + pl * 8 + 0];
    const float py = preds[pb * (LL * 8) + pl * 8 + 1];

    // grid_sample nearest, align_corners=False, zeros padding.
    const float cx = __fsub_rn(__fmul_rn(px, 256.0f), 0.5f);
    const float cy = __fsub_rn(__fmul_rn(py, 256.0f), 0.5f);
    const int ix = (int)rintf(cx);       // round half to even == jnp.rint
    const int iy = (int)rintf(cy);
    const bool valid = (ix >= 0) && (ix < IMG_SIZE) && (iy >= 0) && (iy < IMG_SIZE);
    const int ixc = min(max(ix, 0), IMG_SIZE - 1);
    const int iyc = min(max(iy, 0), IMG_SIZE - 1);
    const float vmul = valid ? 1.0f : 0.0f;

    const float* imgb = imgs + (size_t)b * 3 * NPIX;
    const float c0 = imgb[0 * NPIX + iyc * IMG_SIZE + ixc] * vmul;
    const float c1 = imgb[1 * NPIX + iyc * IMG_SIZE + ixc] * vmul;
    const float c2 = imgb[2 * NPIX + iyc * IMG_SIZE + ixc] * vmul;

    const float4* p0 = (const float4*)(imgb + 0 * NPIX);
    const float4* p1 = (const float4*)(imgb + 1 * NPIX);
    const float4* p2 = (const float4*)(imgb + 2 * NPIX);

    ull loc[KSEL];
    #pragma unroll
    for (int j = 0; j < KSEL; ++j) loc[j] = SENTK;

    const int v0 = split * (CHUNK / 4);

    // ---- Bootstrap: iteration 0 (1024 pixels), unconditional inserts ----
    {
        const int v = v0 + t;
        const float4 r0 = p0[v];
        const float4 r1 = p1[v];
        const float4 r2 = p2[v];
        const int base = v * 4;
        sort_insert(loc, pix_key(r0.x, r1.x, r2.x, c0, c1, c2, base + 0));
        sort_insert(loc, pix_key(r0.y, r1.y, r2.y, c0, c1, c2, base + 1));
        sort_insert(loc, pix_key(r0.z, r1.z, r2.z, c0, c1, c2, base + 2));
        sort_insert(loc, pix_key(r0.w, r1.w, r2.w, c0, c1, c2, base + 3));
    }

    // Block-exact bootstrap threshold via the verified merge5 tree.
    #pragma unroll
    for (int j = 0; j < KSEL; ++j) shm.sk[t * KSEL + j] = loc[j];
    __syncthreads();
    for (int s = NTHREADS / 2; s > 0; s >>= 1) {
        if (t < s) {
            ull a[KSEL], bb[KSEL];
            #pragma unroll
            for (int j = 0; j < KSEL; ++j) { a[j] = shm.sk[t * KSEL + j]; bb[j] = shm.sk[(t + s) * KSEL + j]; }
            merge5(a, bb);
            #pragma unroll
            for (int j = 0; j < KSEL; ++j) shm.sk[t * KSEL + j] = a[j];
        }
        __syncthreads();
    }
    if (t == 0) thrsh = (unsigned)(shm.sk[KSEL - 1] >> 32);   // bits of s5(bootstrap)
    __syncthreads();
    const unsigned thr = thrsh;          // register; sk contents now dead -> qq may reuse
    if (t < 4) wcnt[t] = 0u;             // (re-assert; qq region about to be used)
    __syncthreads();

    // Drain: queue -> per-lane lists. Per-wave LDS ops are in-order, so the
    // reads precede the lane-0 reset that callers issue after this returns.
    auto drain = [&]() {
        const unsigned n = wcnt[wave];
        for (unsigned o = lane; o < n; o += 64) sort_insert(loc, shm.qq[wave][o]);
    };
    // Gate one float4-group: 9-op s per pixel, rare push; no insert/ballot.
    auto gate4 = [&](const float4 r0, const float4 r1, const float4 r2, const int base) {
        const float sx = pix_s(r0.x, r1.x, r2.x, c0, c1, c2);
        const float sy = pix_s(r0.y, r1.y, r2.y, c0, c1, c2);
        const float sz = pix_s(r0.z, r1.z, r2.z, c0, c1, c2);
        const float sw = pix_s(r0.w, r1.w, r2.w, c0, c1, c2);
        if (__float_as_uint(sx) <= thr) {
            const unsigned pos = atomicAdd(&wcnt[wave], 1u);
            shm.qq[wave][pos] = ((ull)__float_as_uint(sx) << 32) | (unsigned)(base + 0);
        }
        if (__float_as_uint(sy) <= thr) {
            const unsigned pos = atomicAdd(&wcnt[wave], 1u);
            shm.qq[wave][pos] = ((ull)__float_as_uint(sy) << 32) | (unsigned)(base + 1);
        }
        if (__float_as_uint(sz) <= thr) {
            const unsigned pos = atomicAdd(&wcnt[wave], 1u);
            shm.qq[wave][pos] = ((ull)__float_as_uint(sz) << 32) | (unsigned)(base + 2);
        }
        if (__float_as_uint(sw) <= thr) {
            const unsigned pos = atomicAdd(&wcnt[wave], 1u);
            shm.qq[wave][pos] = ((ull)__float_as_uint(sw) << 32) | (unsigned)(base + 3);
        }
    };

    // ---- Steady loop: PAIRED iterations — 6 loads in flight, then 2 gated
    //      halves with a queue guard before each half's <=256 pushes ----
    for (int it = 1; it + 1 < NITER; it += 2) {
        if (wcnt[wave] + NTHREADS > QCAP) {
            drain();
            if (lane == 0) wcnt[wave] = 0u;
        }
        const int vA = v0 + it * NTHREADS + t;
        const int vB = vA + NTHREADS;
        const float4 a0 = p0[vA];
        const float4 a1 = p1[vA];
        const float4 a2 = p2[vA];
        const float4 b0 = p0[vB];
        const float4 b1 = p1[vB];
        const float4 b2 = p2[vB];
        gate4(a0, a1, a2, vA * 4);
        if (wcnt[wave] + NTHREADS > QCAP) {
            drain();
            if (lane == 0) wcnt[wave] = 0u;
        }
        gate4(b0, b1, b2, vB * 4);
    }
    // Tail iteration (NITER-1 = 15; 15 steady iterations = 7 pairs + 1).
    {
        if (wcnt[wave] + NTHREADS > QCAP) {
            drain();
            if (lane == 0) wcnt[wave] = 0u;
        }
        const int v = v0 + (NITER - 1) * NTHREADS + t;
        const float4 r0 = p0[v];
        const float4 r1 = p1[v];
        const float4 r2 = p2[v];
        gate4(r0, r1, r2, v * 4);
    }

    // ---- End drain: queue -> per-lane lists (each entry inserted once) ----
    drain();

    // ---- Verified block merge (byte-identical tree) + output ----
    __syncthreads();                     // all waves done draining before sk reuse
    #pragma unroll
    for (int j = 0; j < KSEL; ++j) shm.sk[t * KSEL + j] = loc[j];
    __syncthreads();
    for (int s = NTHREADS / 2; s > 0; s >>= 1) {
        if (t < s) {
            ull a[KSEL], bb[KSEL];
            #pragma unroll
            for (int j = 0; j < KSEL; ++j) { a[j] = shm.sk[t * KSEL + j]; bb[j] = shm.sk[(t + s) * KSEL + j]; }
            merge5(a, bb);
            #pragma unroll
            for (int j = 0; j < KSEL; ++j) shm.sk[t * KSEL + j] = a[j];
        }
        __syncthreads();
    }

    if (t < KSEL) {
        keys_out[((size_t)bid * SPLIT + split) * KSEL + t] = shm.sk[t];
    }
}

// Epilogue (verified, unchanged): merge the SPLIT partial top-5s per row, roll
// along L, min positional distance over the 5 selected pixels, mean.
__global__ __launch_bounds__(NTHREADS)
void finalize_kernel(const float* __restrict__ preds,
                     const ull* __restrict__ keys,
                     float* __restrict__ out) {
    const int t = threadIdx.x;
    float acc = 0.0f;

    for (int p = t; p < BS * LUSED; p += NTHREADS) {
        const int b = p / LUSED;
        const int l = p % LUSED + 1;              // loss rows: l = 1..63
        const float px = preds[b * (LL * 8) + l * 8 + 0];
        const float py = preds[b * (LL * 8) + l * 8 + 1];

        // tgt_down[:, l] = tgt[:, l-1]: merge the SPLIT sorted 5-lists of row l-1.
        const int srow = b * LL + (l - 1);
        ull loc[KSEL];
        #pragma unroll
        for (int j = 0; j < KSEL; ++j) loc[j] = SENTK;
        #pragma unroll
        for (int s = 0; s < SPLIT; ++s) {
            #pragma unroll
            for (int k = 0; k < KSEL; ++k) {
                sort_insert(loc, keys[((size_t)srow * SPLIT + s) * KSEL + k]);
            }
        }

        float best = 3.4028235e38f;
        #pragma unroll
        for (int k = 0; k < KSEL; ++k) {
            const int ixk = (int)(loc[k] & 0xFFFFFFFFULL);
            const float tx = (float)(ixk & 255) * (1.0f / 256.0f);   // exact /256
            const float ty = (float)(ixk >> 8) * (1.0f / 256.0f);
            const float dx = __fsub_rn(px, tx);
            const float dy = __fsub_rn(py, ty);
            const float dist = __fadd_rn(__fmul_rn(dx, dx), __fmul_rn(dy, dy));
            best = dist < best ? dist : best;
        }
        acc += best;
    }

    __shared__ float red[NTHREADS];
    red[t] = acc;
    __syncthreads();
    for (int s = NTHREADS / 2; s > 0; s >>= 1) {
        if (t < s) red[t] += red[t + s];
        __syncthreads();
    }
    if (t == 0) {
        out[0] = red[0] / (float)(BS * (LL - 1));
    }
}

extern "C" void kernel_launch(void* const* d_in, const int* in_sizes, int n_in,
                              void* d_out, int out_size, void* d_ws, size_t ws_size,
                              hipStream_t stream) {
    const float* preds = (const float*)d_in[0];   // (8, 64, 8) f32
    const float* imgs  = (const float*)d_in[1];   // (8, 3, 256, 256) f32
    float* out = (float*)d_out;                   // scalar f32
    ull* keys = (ull*)d_ws;                       // 512 * SPLIT * 5 u64 = 80 KB

    topk_kernel<<<dim3(BS * LUSED * SPLIT), dim3(NTHREADS), 0, stream>>>(preds, imgs, keys);
    finalize_kernel<<<dim3(1), dim3(NTHREADS), 0, stream>>>(preds, keys, out);
}

// Round 17
// 89.450 us; speedup vs baseline: 1.9450x; 1.1513x over previous
//
#include <hip/hip_runtime.h>

#define IMG_SIZE 256
#define NPIX (IMG_SIZE * IMG_SIZE)
#define KSEL 5
#define BS 8
#define LL 64
#define LUSED 63          // row l=63's top-k is discarded by the roll — never compute it
#define NTHREADS 256
#define SPLIT 4           // blocks per (b,l) row
#define CHUNK (NPIX / SPLIT)      // 16384 pixels per block
#define QCAP 320          // per-wave candidate queue; 4*QCAP*8 == NTHREADS*KSEL*8
#define SENTK 0xFFFFFFFFFFFFFFFFULL

typedef unsigned long long ull;

// Branchless sorted-insert: loc[] ascending; bubble key in, evict the max.
// Static indices only -> stays in VGPRs; no divergence.
__device__ __forceinline__ void sort_insert(ull loc[KSEL], ull key) {
    #pragma unroll
    for (int j = 0; j < KSEL; ++j) {
        const ull a = loc[j];
        const bool lt = key < a;
        loc[j] = lt ? key : a;
        key    = lt ? a : key;
    }
}

// Merge two ascending 5-lists, keep smallest 5 into a.
__device__ __forceinline__ void merge5(ull* a, const ull* b) {
    ull out[KSEL];
    int ia = 0, ib = 0;
    #pragma unroll
    for (int j = 0; j < KSEL; ++j) {
        const ull va = a[ia], vb = b[ib];
        const bool ta = va <= vb;
        out[j] = ta ? va : vb;
        ia += ta ? 1 : 0;
        ib += ta ? 0 : 1;
    }
    #pragma unroll
    for (int j = 0; j < KSEL; ++j) a[j] = out[j];
}

// Single source of truth for the SSD: match numpy f32 exactly — no FMA
// contraction, ((d0^2+d1^2)+d2^2). Both the bootstrap keys and the steady-path
// gate use THIS function, so gate-s and key-s are bit-identical.
__device__ __forceinline__ float
pix_s(float r0, float r1, float r2, float c0, float c1, float c2) {
    float d0 = __fsub_rn(r0, c0);
    float d1 = __fsub_rn(r1, c1);
    float d2 = __fsub_rn(r2, c2);
    return __fadd_rn(__fadd_rn(__fmul_rn(d0, d0), __fmul_rn(d1, d1)), __fmul_rn(d2, d2));
}

__device__ __forceinline__ ull
pix_key(float r0, float r1, float r2, float c0, float c1, float c2, int pix) {
    // s >= 0 (sum of squares) -> uint bit order == float order; low bits = pixel
    // index gives jax top_k's lower-index-first tie-break.
    const float s = pix_s(r0, r1, r2, c0, c1, c2);
    return ((ull)__float_as_uint(s) << 32) | (unsigned int)pix;
}

// One block per (b,l,split). EXACT REVERSION to the verified R9 champion
// (89.5us, absmax 0.0): bootstrap 1024 px -> block-exact threshold ->
// gate-to-memory steady loop (9-op s test, rare LDS-queue push) -> drain ->
// verified merge tree. LDS union (sk/qq disjoint live ranges) keeps the block
// at 10.3KB -> 8 blocks/CU, all 2016 blocks co-resident.
// Seven structural variants (R10-R16) all measured slower: flag-barrier
// fusion (L2 storm), XCD swizzle (mapping refuted), RPB=4 (wave starvation),
// RPB=2 bounded (VGPR spill), RPB=2 unbounded (low occ), ILP pairing (spill).
// Exactness:
//   thr = 5th-smallest s over the bootstrap subset >= s5_chunk;
//   admit iff bits(s) <= thr => every true top-5 key is in bootstrap ∪ queue;
//   each pixel enters exactly once => bit-identical top-5.
__global__ __launch_bounds__(NTHREADS)
void topk_kernel(const float* __restrict__ preds,
                 const float* __restrict__ imgs,
                 ull* __restrict__ keys_out) {
    const int blk = blockIdx.x;
    const int split = blk & (SPLIT - 1);
    const int row = blk / SPLIT;         // 0 .. BS*LUSED-1
    const int b = row / LUSED;
    const int l = row % LUSED;
    const int bid = b * LL + l;          // storage row (l < 63)
    const int t = threadIdx.x;
    const int wave = t >> 6;
    const int lane = t & 63;

    __shared__ union ShMem {
        ull sk[NTHREADS * KSEL];         // 10240 B: merge scratch
        ull qq[4][QCAP];                 // 10240 B: per-wave candidate queues
    } shm;
    __shared__ unsigned wcnt[4];
    __shared__ unsigned thrsh;

    if (t < 4) wcnt[t] = 0u;

    // Scrambled pooled indexing: flat i = l*bs + b; position from preds[i//L, i%L].
    const int i = l * BS + b;
    const int pb = i >> 6;
    const int pl = i & 63;
    const float px = preds[pb * (LL * 8) + pl * 8 + 0];
    const float py = preds[pb * (LL * 8) + pl * 8 + 1];

    // grid_sample nearest, align_corners=False, zeros padding.
    const float cx = __fsub_rn(__fmul_rn(px, 256.0f), 0.5f);
    const float cy = __fsub_rn(__fmul_rn(py, 256.0f), 0.5f);
    const int ix = (int)rintf(cx);       // round half to even == jnp.rint
    const int iy = (int)rintf(cy);
    const bool valid = (ix >= 0) && (ix < IMG_SIZE) && (iy >= 0) && (iy < IMG_SIZE);
    const int ixc = min(max(ix, 0), IMG_SIZE - 1);
    const int iyc = min(max(iy, 0), IMG_SIZE - 1);
    const float vmul = valid ? 1.0f : 0.0f;

    const float* imgb = imgs + (size_t)b * 3 * NPIX;
    const float c0 = imgb[0 * NPIX + iyc * IMG_SIZE + ixc] * vmul;
    const float c1 = imgb[1 * NPIX + iyc * IMG_SIZE + ixc] * vmul;
    const float c2 = imgb[2 * NPIX + iyc * IMG_SIZE + ixc] * vmul;

    const float4* p0 = (const float4*)(imgb + 0 * NPIX);
    const float4* p1 = (const float4*)(imgb + 1 * NPIX);
    const float4* p2 = (const float4*)(imgb + 2 * NPIX);

    ull loc[KSEL];
    #pragma unroll
    for (int j = 0; j < KSEL; ++j) loc[j] = SENTK;

    const int v0 = split * (CHUNK / 4);

    // ---- Bootstrap: iteration 0 (1024 pixels), unconditional inserts ----
    {
        const int v = v0 + t;
        const float4 r0 = p0[v];
        const float4 r1 = p1[v];
        const float4 r2 = p2[v];
        const int base = v * 4;
        sort_insert(loc, pix_key(r0.x, r1.x, r2.x, c0, c1, c2, base + 0));
        sort_insert(loc, pix_key(r0.y, r1.y, r2.y, c0, c1, c2, base + 1));
        sort_insert(loc, pix_key(r0.z, r1.z, r2.z, c0, c1, c2, base + 2));
        sort_insert(loc, pix_key(r0.w, r1.w, r2.w, c0, c1, c2, base + 3));
    }

    // Block-exact bootstrap threshold via the verified merge5 tree.
    #pragma unroll
    for (int j = 0; j < KSEL; ++j) shm.sk[t * KSEL + j] = loc[j];
    __syncthreads();
    for (int s = NTHREADS / 2; s > 0; s >>= 1) {
        if (t < s) {
            ull a[KSEL], bb[KSEL];
            #pragma unroll
            for (int j = 0; j < KSEL; ++j) { a[j] = shm.sk[t * KSEL + j]; bb[j] = shm.sk[(t + s) * KSEL + j]; }
            merge5(a, bb);
            #pragma unroll
            for (int j = 0; j < KSEL; ++j) shm.sk[t * KSEL + j] = a[j];
        }
        __syncthreads();
    }
    if (t == 0) thrsh = (unsigned)(shm.sk[KSEL - 1] >> 32);   // bits of s5(bootstrap)
    __syncthreads();
    const unsigned thr = thrsh;          // register; sk contents now dead -> qq may reuse
    if (t < 4) wcnt[t] = 0u;             // (re-assert; qq region about to be used)
    __syncthreads();

    // ---- Steady loop: dense loads, 9-op s + gate, rare queue push ----
    #pragma unroll 2
    for (int it = 1; it < CHUNK / 4 / NTHREADS; ++it) {
        // Overflow safety (wave-uniform; never triggers on random data):
        // guarantee room for this iteration's max 256 pushes (wcnt <= 64 after).
        if (wcnt[wave] + NTHREADS > QCAP) {
            const unsigned n = wcnt[wave];
            for (unsigned o = lane; o < n; o += 64) sort_insert(loc, shm.qq[wave][o]);
            if (lane == 0) wcnt[wave] = 0u;   // per-wave LDS ops are in-order: reads precede
        }
        const int v = v0 + it * NTHREADS + t;
        const float4 r0 = p0[v];
        const float4 r1 = p1[v];
        const float4 r2 = p2[v];
        const int base = v * 4;

        const float sx = pix_s(r0.x, r1.x, r2.x, c0, c1, c2);
        const float sy = pix_s(r0.y, r1.y, r2.y, c0, c1, c2);
        const float sz = pix_s(r0.z, r1.z, r2.z, c0, c1, c2);
        const float sw = pix_s(r0.w, r1.w, r2.w, c0, c1, c2);

        if (__float_as_uint(sx) <= thr) {
            const unsigned pos = atomicAdd(&wcnt[wave], 1u);
            shm.qq[wave][pos] = ((ull)__float_as_uint(sx) << 32) | (unsigned)(base + 0);
        }
        if (__float_as_uint(sy) <= thr) {
            const unsigned pos = atomicAdd(&wcnt[wave], 1u);
            shm.qq[wave][pos] = ((ull)__float_as_uint(sy) << 32) | (unsigned)(base + 1);
        }
        if (__float_as_uint(sz) <= thr) {
            const unsigned pos = atomicAdd(&wcnt[wave], 1u);
            shm.qq[wave][pos] = ((ull)__float_as_uint(sz) << 32) | (unsigned)(base + 2);
        }
        if (__float_as_uint(sw) <= thr) {
            const unsigned pos = atomicAdd(&wcnt[wave], 1u);
            shm.qq[wave][pos] = ((ull)__float_as_uint(sw) << 32) | (unsigned)(base + 3);
        }
    }

    // ---- End drain: queue -> per-lane lists (each entry inserted once) ----
    {
        const unsigned n = wcnt[wave];
        for (unsigned o = lane; o < n; o += 64) sort_insert(loc, shm.qq[wave][o]);
    }

    // ---- Verified block merge (byte-identical tree) + output ----
    __syncthreads();                     // all waves done draining before sk reuse
    #pragma unroll
    for (int j = 0; j < KSEL; ++j) shm.sk[t * KSEL + j] = loc[j];
    __syncthreads();
    for (int s = NTHREADS / 2; s > 0; s >>= 1) {
        if (t < s) {
            ull a[KSEL], bb[KSEL];
            #pragma unroll
            for (int j = 0; j < KSEL; ++j) { a[j] = shm.sk[t * KSEL + j]; bb[j] = shm.sk[(t + s) * KSEL + j]; }
            merge5(a, bb);
            #pragma unroll
            for (int j = 0; j < KSEL; ++j) shm.sk[t * KSEL + j] = a[j];
        }
        __syncthreads();
    }

    if (t < KSEL) {
        keys_out[((size_t)bid * SPLIT + split) * KSEL + t] = shm.sk[t];
    }
}

// Epilogue (verified, unchanged): merge the SPLIT partial top-5s per row, roll
// along L, min positional distance over the 5 selected pixels, mean.
__global__ __launch_bounds__(NTHREADS)
void finalize_kernel(const float* __restrict__ preds,
                     const ull* __restrict__ keys,
                     float* __restrict__ out) {
    const int t = threadIdx.x;
    float acc = 0.0f;

    for (int p = t; p < BS * LUSED; p += NTHREADS) {
        const int b = p / LUSED;
        const int l = p % LUSED + 1;              // loss rows: l = 1..63
        const float px = preds[b * (LL * 8) + l * 8 + 0];
        const float py = preds[b * (LL * 8) + l * 8 + 1];

        // tgt_down[:, l] = tgt[:, l-1]: merge the SPLIT sorted 5-lists of row l-1.
        const int srow = b * LL + (l - 1);
        ull loc[KSEL];
        #pragma unroll
        for (int j = 0; j < KSEL; ++j) loc[j] = SENTK;
        #pragma unroll
        for (int s = 0; s < SPLIT; ++s) {
            #pragma unroll
            for (int k = 0; k < KSEL; ++k) {
                sort_insert(loc, keys[((size_t)srow * SPLIT + s) * KSEL + k]);
            }
        }

        float best = 3.4028235e38f;
        #pragma unroll
        for (int k = 0; k < KSEL; ++k) {
            const int ixk = (int)(loc[k] & 0xFFFFFFFFULL);
            const float tx = (float)(ixk & 255) * (1.0f / 256.0f);   // exact /256
            const float ty = (float)(ixk >> 8) * (1.0f / 256.0f);
            const float dx = __fsub_rn(px, tx);
            const float dy = __fsub_rn(py, ty);
            const float dist = __fadd_rn(__fmul_rn(dx, dx), __fmul_rn(dy, dy));
            best = dist < best ? dist : best;
        }
        acc += best;
    }

    __shared__ float red[NTHREADS];
    red[t] = acc;
    __syncthreads();
    for (int s = NTHREADS / 2; s > 0; s >>= 1) {
        if (t < s) red[t] += red[t + s];
        __syncthreads();
    }
    if (t == 0) {
        out[0] = red[0] / (float)(BS * (LL - 1));
    }
}

extern "C" void kernel_launch(void* const* d_in, const int* in_sizes, int n_in,
                              void* d_out, int out_size, void* d_ws, size_t ws_size,
                              hipStream_t stream) {
    const float* preds = (const float*)d_in[0];   // (8, 64, 8) f32
    const float* imgs  = (const float*)d_in[1];   // (8, 3, 256, 256) f32
    float* out = (float*)d_out;                   // scalar f32
    ull* keys = (ull*)d_ws;                       // 512 * SPLIT * 5 u64 = 80 KB

    topk_kernel<<<dim3(BS * LUSED * SPLIT), dim3(NTHREADS), 0, stream>>>(preds, imgs, keys);
    finalize_kernel<<<dim3(1), dim3(NTHREADS), 0, stream>>>(preds, keys, out);
}